// Round 3
// baseline (605.800 us; speedup 1.0000x reference)
//
#include <hip/hip_runtime.h>

// GCN: out = A*(relu(A*(X*W1)+b1)*W2)+b2, A sparse COO, sorted row[].
// N=100000, E=3200000, IN=256, HID=256, OUT=64.
// Pipeline (7 launches, XCD-sliced spmm):
//   setup: rowptr + W1T + W2T
//   gemm1: Q1,s1 = u8rowquant(bf16(X)@W1), Q1 sliced [8][N][32]
//   prep:  ewc = {w15 | col17} packed 4B  (w = vals*s1[col])
//   spmm1: H = relu(A@deq(Q1)+b1), 8 feature-slices, slice s -> XCD s
//   gemm2: Q2,s2 = u8rowquant(H@W2), Q2 sliced [2][N][32]
//   prep:  ewc = {w15 | col17}            (w = vals*s2[col])
//   spmm2: out = A@deq(Q2)+b2, 2 slices on even/odd XCDs
// Why sliced: Q1 (25.6MB) >> per-XCD L2 (4MB) -> random gather misses at
// ~3.45 TB/s fabric ceiling (measured invariant r0/r2). A 3.2MB slice is
// L2-resident per XCD; metadata re-read (4B/edge/slice) streams nontemporal.
// Q biased-u8: unpack = v_cvt_f32_ubyteN, exact fixup acc - 128*sumw.

constexpr int IN_SIZE = 256;
constexpr int HID = 256;
constexpr int OUTF = 64;

typedef __bf16 bf16x8 __attribute__((ext_vector_type(8)));
typedef float f32x4 __attribute__((ext_vector_type(4)));
typedef uint u32x4 __attribute__((ext_vector_type(4)));

__device__ __forceinline__ ushort f2b(float f) {
    uint u = __float_as_uint(f);
    uint r = (u + 0x7fffu + ((u >> 16) & 1u)) >> 16;   // RNE
    return (ushort)r;
}

// ---------------------------------------------------------------------------
// setup: blocks [0,rpB): row_ptr; [rpB,rpB+256): W1T; [rpB+256,rpB+320): W2T
__global__ void setup_kernel(const int* __restrict__ row, int* __restrict__ rp,
                             const float* __restrict__ W1, ushort* __restrict__ W1T,
                             const float* __restrict__ W2, ushort* __restrict__ W2T,
                             int n, int E, int rpB) {
    int b = blockIdx.x;
    if (b < rpB) {
        int i = b * 256 + threadIdx.x;
        if (i > n) return;
        int lo = 0, hi = E;
        while (lo < hi) {
            int mid = (lo + hi) >> 1;
            if (row[mid] < i) lo = mid + 1; else hi = mid;
        }
        rp[i] = lo;
    } else if (b < rpB + 256) {
        int nn = b - rpB;
        int k = threadIdx.x;
        W1T[(size_t)nn * 256 + k] = f2b(W1[(size_t)k * 256 + nn]);
    } else {
        int nn = b - rpB - 256;
        int k = threadIdx.x;
        W2T[(size_t)nn * 256 + k] = f2b(W2[(size_t)k * 64 + nn]);
    }
}

// prep_pack: ewc[e] = {w top-15 bits (sign+exp+6 mant, rounded) | col 17 bits}
// w = vals[e]*s[col[e]] >= 0; col < 2^17 (N=100000).
__global__ void prep_pack(const float* __restrict__ vals, const int* __restrict__ col,
                          const float* __restrict__ s, uint* __restrict__ ewc, int E) {
    int e = blockIdx.x * 256 + threadIdx.x;
    if (e >= E) return;
    int c = col[e];
    float w = vals[e] * s[c];
    uint wb = (__float_as_uint(w) + 0x10000u) & 0xFFFE0000u;  // round-half-up @ bit17
    ewc[e] = wb | (uint)c;
}

// ---------------------------------------------------------------------------
// GEMM1+quant: Q[8][M][32] biased-u8 (sliced), s1[M] from bf16(X)@Bt^T.
// BM=128, BN=256, BK=32. 512 threads = 8 waves 2x4; pipelined K-loop.
__global__ __launch_bounds__(512)
void gemm1_q(const float* __restrict__ A, const ushort* __restrict__ Bt,
             unsigned char* __restrict__ Q, float* __restrict__ s1, int M) {
    constexpr int K = 256;
    __shared__ ushort As[128 * 40];
    __shared__ ushort Bs[256 * 40];
    __shared__ float red[4][128];
    __shared__ float fin[128];
    const int tid = threadIdx.x;
    const int wave = tid >> 6, lane = tid & 63;
    const int quad = lane >> 4, l = lane & 15;
    const int wr = wave >> 2, wc = wave & 3;
    const int m0 = blockIdx.x * 128;
    const size_t sstr = (size_t)M * 32;   // slice stride

    const int ar = tid >> 2;
    const int ak = (tid & 3) * 8;
    const size_t aoff = (size_t)min(m0 + ar, M - 1) * K + ak;
    const int bn = tid >> 2;
    const int bkp = (tid & 3) * 8;
    const size_t boff0 = (size_t)bn * K + bkp;
    const size_t boff1 = (size_t)(bn + 128) * K + bkp;

    f32x4 acc[4][4] = {};

    float4 a0 = *(const float4*)(A + aoff);
    float4 a1 = *(const float4*)(A + aoff + 4);
    uint4 bv0 = *(const uint4*)(Bt + boff0);
    uint4 bv1 = *(const uint4*)(Bt + boff1);

    for (int k0 = 0; k0 < K; k0 += 32) {
        uint4 pa;
        pa.x = (uint)f2b(a0.x) | ((uint)f2b(a0.y) << 16);
        pa.y = (uint)f2b(a0.z) | ((uint)f2b(a0.w) << 16);
        pa.z = (uint)f2b(a1.x) | ((uint)f2b(a1.y) << 16);
        pa.w = (uint)f2b(a1.z) | ((uint)f2b(a1.w) << 16);
        __syncthreads();
        *(uint4*)&As[ar * 40 + ak] = pa;
        *(uint4*)&Bs[bn * 40 + bkp] = bv0;
        *(uint4*)&Bs[(bn + 128) * 40 + bkp] = bv1;
        __syncthreads();

        if (k0 + 32 < K) {
            a0 = *(const float4*)(A + aoff + k0 + 32);
            a1 = *(const float4*)(A + aoff + k0 + 36);
            bv0 = *(const uint4*)(Bt + boff0 + k0 + 32);
            bv1 = *(const uint4*)(Bt + boff1 + k0 + 32);
        }

        bf16x8 af[4], bfr[4];
#pragma unroll
        for (int mt = 0; mt < 4; ++mt)
            af[mt] = *(const bf16x8*)&As[(wr * 64 + mt * 16 + l) * 40 + quad * 8];
#pragma unroll
        for (int nt = 0; nt < 4; ++nt)
            bfr[nt] = *(const bf16x8*)&Bs[(wc * 64 + nt * 16 + l) * 40 + quad * 8];
#pragma unroll
        for (int mt = 0; mt < 4; ++mt)
#pragma unroll
            for (int nt = 0; nt < 4; ++nt)
                acc[mt][nt] = __builtin_amdgcn_mfma_f32_16x16x32_bf16(
                    af[mt], bfr[nt], acc[mt][nt], 0, 0, 0);
    }

    float rmax[4][4];
#pragma unroll
    for (int mt = 0; mt < 4; ++mt)
#pragma unroll
        for (int reg = 0; reg < 4; ++reg) {
            float m = 0.f;
#pragma unroll
            for (int nt = 0; nt < 4; ++nt)
                m = fmaxf(m, fabsf(acc[mt][nt][reg]));
            rmax[mt][reg] = m;
        }
#pragma unroll
    for (int s = 1; s <= 8; s <<= 1)
#pragma unroll
        for (int mt = 0; mt < 4; ++mt)
#pragma unroll
            for (int reg = 0; reg < 4; ++reg)
                rmax[mt][reg] = fmaxf(rmax[mt][reg], __shfl_xor(rmax[mt][reg], s));
    if (l < 4) {
#pragma unroll
        for (int mt = 0; mt < 4; ++mt)
            red[wc][wr * 64 + mt * 16 + quad * 4 + l] = rmax[mt][l];
    }
    __syncthreads();
    if (tid < 128) {
        float m = fmaxf(fmaxf(red[0][tid], red[1][tid]),
                        fmaxf(red[2][tid], red[3][tid]));
        fin[tid] = m;
        int r = m0 + tid;
        if (r < M) s1[r] = m * (1.f / 127.f);
    }
    __syncthreads();

#pragma unroll
    for (int mt = 0; mt < 4; ++mt)
#pragma unroll
        for (int reg = 0; reg < 4; ++reg) {
            int rl = wr * 64 + mt * 16 + quad * 4 + reg;
            int r = m0 + rl;
            if (r >= M) continue;
            float m = fin[rl];
            float inv = m > 0.f ? 127.f / m : 0.f;
#pragma unroll
            for (int nt = 0; nt < 4; ++nt) {
                int c = wc * 64 + nt * 16 + l;
                Q[(size_t)(c >> 5) * sstr + (size_t)r * 32 + (c & 31)] =
                    (unsigned char)((int)rintf(acc[mt][nt][reg] * inv) + 128);
            }
        }
}

// ---------------------------------------------------------------------------
// GEMM2+quant: Q[2][M][32] biased-u8 (sliced), s2[M] from H bf16 @ Bt^T.
__global__ __launch_bounds__(256, 4)
void gemm2_q(const ushort* __restrict__ A, const ushort* __restrict__ Bt,
             unsigned char* __restrict__ Q, float* __restrict__ s2, int M) {
    constexpr int K = 256;
    __shared__ ushort As[128 * 40];
    __shared__ ushort Bs[64 * 40];
    __shared__ float red[2][128];
    __shared__ float fin[128];
    const int tid = threadIdx.x;
    const int wave = tid >> 6, lane = tid & 63;
    const int quad = lane >> 4, l = lane & 15;
    const int wr = wave >> 1, wc = wave & 1;
    const int m0 = blockIdx.x * 128;
    const size_t sstr = (size_t)M * 32;

    const int crow = tid >> 2;
    const int cpart = (tid & 3) * 8;
    const size_t aoff0 = (size_t)min(m0 + crow, M - 1) * K + cpart;
    const size_t aoff1 = (size_t)min(m0 + crow + 64, M - 1) * K + cpart;
    const size_t boff  = (size_t)crow * K + cpart;

    f32x4 acc[4][2] = {};

    uint4 a0 = *(const uint4*)(A + aoff0);
    uint4 a1 = *(const uint4*)(A + aoff1);
    uint4 b0 = *(const uint4*)(Bt + boff);

    for (int k0 = 0; k0 < K; k0 += 32) {
        __syncthreads();
        *(uint4*)&As[crow * 40 + cpart] = a0;
        *(uint4*)&As[(crow + 64) * 40 + cpart] = a1;
        *(uint4*)&Bs[crow * 40 + cpart] = b0;
        __syncthreads();

        if (k0 + 32 < K) {
            a0 = *(const uint4*)(A + aoff0 + k0 + 32);
            a1 = *(const uint4*)(A + aoff1 + k0 + 32);
            b0 = *(const uint4*)(Bt + boff + k0 + 32);
        }

        bf16x8 af[4], bfr[2];
        const ushort* ab = &As[(wr * 64 + l) * 40 + quad * 8];
#pragma unroll
        for (int mt = 0; mt < 4; ++mt)
            af[mt] = *(const bf16x8*)(ab + mt * 16 * 40);
        const ushort* bb = &Bs[(wc * 32 + l) * 40 + quad * 8];
#pragma unroll
        for (int nt = 0; nt < 2; ++nt)
            bfr[nt] = *(const bf16x8*)(bb + nt * 16 * 40);
#pragma unroll
        for (int mt = 0; mt < 4; ++mt)
#pragma unroll
            for (int nt = 0; nt < 2; ++nt)
                acc[mt][nt] = __builtin_amdgcn_mfma_f32_16x16x32_bf16(
                    af[mt], bfr[nt], acc[mt][nt], 0, 0, 0);
    }

    float rmax[4][4];
#pragma unroll
    for (int mt = 0; mt < 4; ++mt)
#pragma unroll
        for (int reg = 0; reg < 4; ++reg)
            rmax[mt][reg] = fmaxf(fabsf(acc[mt][0][reg]), fabsf(acc[mt][1][reg]));
#pragma unroll
    for (int s = 1; s <= 8; s <<= 1)
#pragma unroll
        for (int mt = 0; mt < 4; ++mt)
#pragma unroll
            for (int reg = 0; reg < 4; ++reg)
                rmax[mt][reg] = fmaxf(rmax[mt][reg], __shfl_xor(rmax[mt][reg], s));
    if (l < 4) {
#pragma unroll
        for (int mt = 0; mt < 4; ++mt)
            red[wc][wr * 64 + mt * 16 + quad * 4 + l] = rmax[mt][l];
    }
    __syncthreads();
    if (tid < 128) {
        float m = fmaxf(red[0][tid], red[1][tid]);
        fin[tid] = m;
        int r = m0 + tid;
        if (r < M) s2[r] = m * (1.f / 127.f);
    }
    __syncthreads();

#pragma unroll
    for (int mt = 0; mt < 4; ++mt)
#pragma unroll
        for (int reg = 0; reg < 4; ++reg) {
            int rl = wr * 64 + mt * 16 + quad * 4 + reg;
            int r = m0 + rl;
            if (r >= M) continue;
            float m = fin[rl];
            float inv = m > 0.f ? 127.f / m : 0.f;
#pragma unroll
            for (int nt = 0; nt < 2; ++nt) {
                int c = wc * 32 + nt * 16 + l;
                Q[(size_t)(c >> 5) * sstr + (size_t)r * 32 + (c & 31)] =
                    (unsigned char)((int)rintf(acc[mt][nt][reg] * inv) + 128);
            }
        }
}

// ---------------------------------------------------------------------------
// SpMM layer1, XCD-sliced: slice = bid&7 -> XCD (bid%8 round-robin). Each
// slice gathers only from its 3.2MB Q-slice (L2-resident). Wave = 2 nodes
// (32 lanes each): 8 edge slots x 4 feat-lanes x 8 features. 2x unrolled,
// fully masked loop. Metadata/output use nontemporal to protect L2.
__global__ __launch_bounds__(256)
void spmm1_s(const unsigned char* __restrict__ Q, const uint* __restrict__ ewc,
             const int* __restrict__ rp, const float* __restrict__ bias,
             ushort* __restrict__ H, int n) {
    const int slice = blockIdx.x & 7;
    const int nb = blockIdx.x >> 3;
    const int wave = threadIdx.x >> 6;
    const int lane = threadIdx.x & 63;
    const int hl = lane & 31;          // lane within half
    const int g = hl >> 2;             // edge slot 0..7
    const int fl = lane & 3;           // feature quarter: 8 feats at fl*8
    const int fb = fl * 8;
    const int node = nb * 8 + wave * 2 + (lane >> 5);
    const unsigned char* Qs = Q + (size_t)slice * ((size_t)n << 5);

    int e0 = 0, e1 = 0;
    if (node < n) { e0 = rp[node]; e1 = rp[node + 1]; }
    int deg = e1 - e0;
    int dmax = max(deg, __shfl_xor(deg, 32));

    float acc[8] = {};
    float sumw = 0.f;
    int eh = e0 + g;
    for (int it = (dmax + 15) >> 4; it > 0; --it, eh += 16) {
        bool ok0 = eh < e1;
        bool ok1 = eh + 8 < e1;
        uint p0 = __builtin_nontemporal_load(ewc + (ok0 ? eh : 0));
        uint p1 = __builtin_nontemporal_load(ewc + (ok1 ? eh + 8 : 0));
        float w0 = ok0 ? __uint_as_float(p0 & 0xFFFE0000u) : 0.f;
        float w1 = ok1 ? __uint_as_float(p1 & 0xFFFE0000u) : 0.f;
        uint of0 = (ok0 ? ((p0 & 0x1FFFFu) << 5) : 0u) + fb;
        uint of1 = (ok1 ? ((p1 & 0x1FFFFu) << 5) : 0u) + fb;
        uint2 q0 = *(const uint2*)(Qs + of0);
        uint2 q1 = *(const uint2*)(Qs + of1);
        sumw += w0 + w1;
        acc[0] += w0 * (float)(q0.x & 0xffu)         + w1 * (float)(q1.x & 0xffu);
        acc[1] += w0 * (float)((q0.x >> 8) & 0xffu)  + w1 * (float)((q1.x >> 8) & 0xffu);
        acc[2] += w0 * (float)((q0.x >> 16) & 0xffu) + w1 * (float)((q1.x >> 16) & 0xffu);
        acc[3] += w0 * (float)(q0.x >> 24)           + w1 * (float)(q1.x >> 24);
        acc[4] += w0 * (float)(q0.y & 0xffu)         + w1 * (float)(q1.y & 0xffu);
        acc[5] += w0 * (float)((q0.y >> 8) & 0xffu)  + w1 * (float)((q1.y >> 8) & 0xffu);
        acc[6] += w0 * (float)((q0.y >> 16) & 0xffu) + w1 * (float)((q1.y >> 16) & 0xffu);
        acc[7] += w0 * (float)(q0.y >> 24)           + w1 * (float)(q1.y >> 24);
    }

    // reduce over 8 edge slots within each 32-lane half
#pragma unroll
    for (int s = 4; s <= 16; s <<= 1) {
#pragma unroll
        for (int j = 0; j < 8; ++j)
            acc[j] += __shfl_xor(acc[j], s);
        sumw += __shfl_xor(sumw, s);
    }

    if (g == 0 && node < n) {
        const float* bp = bias + slice * 32 + fb;
        float fix = -128.f * sumw;
        ushort r[8];
#pragma unroll
        for (int j = 0; j < 8; ++j)
            r[j] = f2b(fmaxf(acc[j] + fix + bp[j], 0.f));
        u32x4 wv;
        wv.x = (uint)r[0] | ((uint)r[1] << 16);
        wv.y = (uint)r[2] | ((uint)r[3] << 16);
        wv.z = (uint)r[4] | ((uint)r[5] << 16);
        wv.w = (uint)r[6] | ((uint)r[7] << 16);
        __builtin_nontemporal_store(wv,
            (u32x4*)(H + (size_t)node * 256 + slice * 32 + fb));
    }
}

// ---------------------------------------------------------------------------
// SpMM layer2, 2 slices (even/odd XCDs). Same structure; fp32 out, no relu.
__global__ __launch_bounds__(256)
void spmm2_s(const unsigned char* __restrict__ Q, const uint* __restrict__ ewc,
             const int* __restrict__ rp, const float* __restrict__ bias,
             float* __restrict__ O, int n) {
    const int slice = blockIdx.x & 1;
    const int nb = blockIdx.x >> 1;
    const int wave = threadIdx.x >> 6;
    const int lane = threadIdx.x & 63;
    const int hl = lane & 31;
    const int g = hl >> 2;
    const int fl = lane & 3;
    const int fb = fl * 8;
    const int node = nb * 8 + wave * 2 + (lane >> 5);
    const unsigned char* Qs = Q + (size_t)slice * ((size_t)n << 5);

    int e0 = 0, e1 = 0;
    if (node < n) { e0 = rp[node]; e1 = rp[node + 1]; }
    int deg = e1 - e0;
    int dmax = max(deg, __shfl_xor(deg, 32));

    float acc[8] = {};
    float sumw = 0.f;
    int eh = e0 + g;
    for (int it = (dmax + 15) >> 4; it > 0; --it, eh += 16) {
        bool ok0 = eh < e1;
        bool ok1 = eh + 8 < e1;
        uint p0 = __builtin_nontemporal_load(ewc + (ok0 ? eh : 0));
        uint p1 = __builtin_nontemporal_load(ewc + (ok1 ? eh + 8 : 0));
        float w0 = ok0 ? __uint_as_float(p0 & 0xFFFE0000u) : 0.f;
        float w1 = ok1 ? __uint_as_float(p1 & 0xFFFE0000u) : 0.f;
        uint of0 = (ok0 ? ((p0 & 0x1FFFFu) << 5) : 0u) + fb;
        uint of1 = (ok1 ? ((p1 & 0x1FFFFu) << 5) : 0u) + fb;
        uint2 q0 = *(const uint2*)(Qs + of0);
        uint2 q1 = *(const uint2*)(Qs + of1);
        sumw += w0 + w1;
        acc[0] += w0 * (float)(q0.x & 0xffu)         + w1 * (float)(q1.x & 0xffu);
        acc[1] += w0 * (float)((q0.x >> 8) & 0xffu)  + w1 * (float)((q1.x >> 8) & 0xffu);
        acc[2] += w0 * (float)((q0.x >> 16) & 0xffu) + w1 * (float)((q1.x >> 16) & 0xffu);
        acc[3] += w0 * (float)(q0.x >> 24)           + w1 * (float)(q1.x >> 24);
        acc[4] += w0 * (float)(q0.y & 0xffu)         + w1 * (float)(q1.y & 0xffu);
        acc[5] += w0 * (float)((q0.y >> 8) & 0xffu)  + w1 * (float)((q1.y >> 8) & 0xffu);
        acc[6] += w0 * (float)((q0.y >> 16) & 0xffu) + w1 * (float)((q1.y >> 16) & 0xffu);
        acc[7] += w0 * (float)(q0.y >> 24)           + w1 * (float)(q1.y >> 24);
    }

#pragma unroll
    for (int s = 4; s <= 16; s <<= 1) {
#pragma unroll
        for (int j = 0; j < 8; ++j)
            acc[j] += __shfl_xor(acc[j], s);
        sumw += __shfl_xor(sumw, s);
    }

    if (g == 0 && node < n) {
        const float* bp = bias + slice * 32 + fb;
        float fix = -128.f * sumw;
        f32x4 o0, o1;
        o0.x = acc[0] + fix + bp[0];
        o0.y = acc[1] + fix + bp[1];
        o0.z = acc[2] + fix + bp[2];
        o0.w = acc[3] + fix + bp[3];
        o1.x = acc[4] + fix + bp[4];
        o1.y = acc[5] + fix + bp[5];
        o1.z = acc[6] + fix + bp[6];
        o1.w = acc[7] + fix + bp[7];
        float* op = O + (size_t)node * 64 + slice * 32 + fb;
        __builtin_nontemporal_store(o0, (f32x4*)op);
        __builtin_nontemporal_store(o1, (f32x4*)(op + 4));
    }
}

// ---------------------------------------------------------------------------
static inline size_t alignup(size_t x) { return (x + 255) & ~(size_t)255; }

extern "C" void kernel_launch(void* const* d_in, const int* in_sizes, int n_in,
                              void* d_out, int out_size, void* d_ws, size_t ws_size,
                              hipStream_t stream) {
    const float* X  = (const float*)d_in[0];
    const float* ev = (const float*)d_in[1];
    const float* W1 = (const float*)d_in[2];
    const float* b1 = (const float*)d_in[3];
    const float* W2 = (const float*)d_in[4];
    const float* b2 = (const float*)d_in[5];
    const int*  row = (const int*)d_in[6];
    const int*  col = (const int*)d_in[7];
    float* out = (float*)d_out;

    const int n = in_sizes[0] / IN_SIZE;   // 100000
    const int E = in_sizes[1];             // 3200000

    char* p = (char*)d_ws;
    ushort* H    = (ushort*)p; p += alignup((size_t)n * HID * 2);
    unsigned char* Q1 = (unsigned char*)p; p += alignup((size_t)n * HID);
    float*  s1   = (float*)p;  p += alignup((size_t)n * 4);
    unsigned char* Q2 = (unsigned char*)p; p += alignup((size_t)n * OUTF);
    float*  s2   = (float*)p;  p += alignup((size_t)n * 4);
    ushort* W1T  = (ushort*)p; p += alignup((size_t)IN_SIZE * HID * 2);
    ushort* W2T  = (ushort*)p; p += alignup((size_t)HID * OUTF * 2);
    int*    rp   = (int*)p;    p += alignup((size_t)(n + 1) * 4);
    uint*   ewc  = (uint*)p;   p += alignup((size_t)E * 4);

    const int rpB = (n + 1 + 255) / 256;
    setup_kernel<<<rpB + 256 + 64, 256, 0, stream>>>(row, rp, W1, W1T, W2, W2T,
                                                     n, E, rpB);

    // Q1,s1 = u8rowquant(bf16(X) @ W1), sliced [8][n][32]
    gemm1_q<<<(n + 127) / 128, 512, 0, stream>>>(X, W1T, Q1, s1, n);

    // ewc = {w15|col17}, w = vals*s1[col]
    prep_pack<<<(E + 255) / 256, 256, 0, stream>>>(ev, col, s1, ewc, E);

    // H = relu(A @ deq(Q1) + b1), 8 slices -> 8 XCDs
    const int nb1 = (n + 7) / 8;
    spmm1_s<<<nb1 * 8, 256, 0, stream>>>(Q1, ewc, rp, b1, H, n);

    // Q2,s2 = u8rowquant(H @ W2), sliced [2][n][32]
    gemm2_q<<<(n + 127) / 128, 256, 0, stream>>>(H, W2T, Q2, s2, n);

    // ewc = {w15|col17}, w = vals*s2[col]
    prep_pack<<<(E + 255) / 256, 256, 0, stream>>>(ev, col, s2, ewc, E);

    // out = A @ deq(Q2) + b2, 2 slices on even/odd XCDs
    spmm2_s<<<nb1 * 2, 256, 0, stream>>>(Q2, ewc, rp, b2, out, n);
}

// Round 4
// 471.633 us; speedup vs baseline: 1.2845x; 1.2845x over previous
//
#include <hip/hip_runtime.h>

// GCN: out = A*(relu(A*(X*W1)+b1)*W2)+b2, A sparse COO, sorted row[].
// N=100000, E=3200000, IN=256, HID=256, OUT=64.
// Pipeline (7 launches, wide-gather spmm, biased-uint8 Q, 4B packed meta):
//   setup: rowptr + W1T + W2T
//   gemm1: Q1,s1 = u8rowquant(bf16(X)@W1)     (512thr, BM=128 BN=256)
//   prep:  ewc = {w15 | col17} packed 4B      (w = vals*s1[col])
//   spmm1: H = relu(A@deq(Q1)+b1) -> bf16     (4 edges/gather, 16B/lane)
//   gemm2: Q2,s2 = u8rowquant(H@W2)           (256thr, BM=128 BN=64)
//   prep:  ewc = {w15 | col17}                (w = vals*s2[col])
//   spmm2: out = A@deq(Q2)+b2 -> fp32         (8 edges/gather, 8B/lane)
// Key r4 change: meta loads + H/out stores are NONTEMPORAL so the 12.8MB
// meta stream and 50MB output stream stop evicting Q from L2 (r0/r2
// measured Q hit only ~57%; FETCH 360MB >> 103MB compulsory). Q gathers
// keep normal caching. Q biased-u8: unpack = v_cvt_f32_ubyteN, exact
// fixup acc - 128*sumw.

constexpr int IN_SIZE = 256;
constexpr int HID = 256;
constexpr int OUTF = 64;

typedef __bf16 bf16x8 __attribute__((ext_vector_type(8)));
typedef float f32x4 __attribute__((ext_vector_type(4)));
typedef uint u32x4 __attribute__((ext_vector_type(4)));

__device__ __forceinline__ ushort f2b(float f) {
    uint u = __float_as_uint(f);
    uint r = (u + 0x7fffu + ((u >> 16) & 1u)) >> 16;   // RNE
    return (ushort)r;
}

__device__ __forceinline__ void fma4(float* a, uint word, float w) {
    a[0] += w * (float)(word & 0xffu);
    a[1] += w * (float)((word >> 8) & 0xffu);
    a[2] += w * (float)((word >> 16) & 0xffu);
    a[3] += w * (float)(word >> 24);
}

// ---------------------------------------------------------------------------
// setup: blocks [0,rpB): row_ptr; [rpB,rpB+256): W1T; [rpB+256,rpB+320): W2T
__global__ void setup_kernel(const int* __restrict__ row, int* __restrict__ rp,
                             const float* __restrict__ W1, ushort* __restrict__ W1T,
                             const float* __restrict__ W2, ushort* __restrict__ W2T,
                             int n, int E, int rpB) {
    int b = blockIdx.x;
    if (b < rpB) {
        int i = b * 256 + threadIdx.x;
        if (i > n) return;
        int lo = 0, hi = E;
        while (lo < hi) {
            int mid = (lo + hi) >> 1;
            if (row[mid] < i) lo = mid + 1; else hi = mid;
        }
        rp[i] = lo;
    } else if (b < rpB + 256) {
        int nn = b - rpB;
        int k = threadIdx.x;
        W1T[(size_t)nn * 256 + k] = f2b(W1[(size_t)k * 256 + nn]);
    } else {
        int nn = b - rpB - 256;
        int k = threadIdx.x;
        W2T[(size_t)nn * 256 + k] = f2b(W2[(size_t)k * 64 + nn]);
    }
}

// prep_pack: ewc[e] = {w top-15 bits (sign+exp+6 mant, rounded) | col 17 bits}
// w = vals[e]*s[col[e]] >= 0; col < 2^17 (N=100000).
__global__ void prep_pack(const float* __restrict__ vals, const int* __restrict__ col,
                          const float* __restrict__ s, uint* __restrict__ ewc, int E) {
    int e = blockIdx.x * 256 + threadIdx.x;
    if (e >= E) return;
    int c = col[e];
    float w = vals[e] * s[c];
    uint wb = (__float_as_uint(w) + 0x10000u) & 0xFFFE0000u;  // round-half-up @ bit17
    ewc[e] = wb | (uint)c;
}

// ---------------------------------------------------------------------------
// GEMM1+quant: Q[M,256] biased-u8, s1[M] from bf16(X_f32[M,256]) @ Bt^T.
// BM=128, BN=256, BK=32. 512 threads = 8 waves 2x4; pipelined K-loop.
__global__ __launch_bounds__(512)
void gemm1_q(const float* __restrict__ A, const ushort* __restrict__ Bt,
             unsigned char* __restrict__ Q, float* __restrict__ s1, int M) {
    constexpr int K = 256;
    __shared__ ushort As[128 * 40];
    __shared__ ushort Bs[256 * 40];
    __shared__ float red[4][128];
    __shared__ float fin[128];
    const int tid = threadIdx.x;
    const int wave = tid >> 6, lane = tid & 63;
    const int quad = lane >> 4, l = lane & 15;
    const int wr = wave >> 2, wc = wave & 3;
    const int m0 = blockIdx.x * 128;

    const int ar = tid >> 2;
    const int ak = (tid & 3) * 8;
    const size_t aoff = (size_t)min(m0 + ar, M - 1) * K + ak;
    const int bn = tid >> 2;
    const int bkp = (tid & 3) * 8;
    const size_t boff0 = (size_t)bn * K + bkp;
    const size_t boff1 = (size_t)(bn + 128) * K + bkp;

    f32x4 acc[4][4] = {};

    float4 a0 = *(const float4*)(A + aoff);
    float4 a1 = *(const float4*)(A + aoff + 4);
    uint4 bv0 = *(const uint4*)(Bt + boff0);
    uint4 bv1 = *(const uint4*)(Bt + boff1);

    for (int k0 = 0; k0 < K; k0 += 32) {
        uint4 pa;
        pa.x = (uint)f2b(a0.x) | ((uint)f2b(a0.y) << 16);
        pa.y = (uint)f2b(a0.z) | ((uint)f2b(a0.w) << 16);
        pa.z = (uint)f2b(a1.x) | ((uint)f2b(a1.y) << 16);
        pa.w = (uint)f2b(a1.z) | ((uint)f2b(a1.w) << 16);
        __syncthreads();
        *(uint4*)&As[ar * 40 + ak] = pa;
        *(uint4*)&Bs[bn * 40 + bkp] = bv0;
        *(uint4*)&Bs[(bn + 128) * 40 + bkp] = bv1;
        __syncthreads();

        if (k0 + 32 < K) {
            a0 = *(const float4*)(A + aoff + k0 + 32);
            a1 = *(const float4*)(A + aoff + k0 + 36);
            bv0 = *(const uint4*)(Bt + boff0 + k0 + 32);
            bv1 = *(const uint4*)(Bt + boff1 + k0 + 32);
        }

        bf16x8 af[4], bfr[4];
#pragma unroll
        for (int mt = 0; mt < 4; ++mt)
            af[mt] = *(const bf16x8*)&As[(wr * 64 + mt * 16 + l) * 40 + quad * 8];
#pragma unroll
        for (int nt = 0; nt < 4; ++nt)
            bfr[nt] = *(const bf16x8*)&Bs[(wc * 64 + nt * 16 + l) * 40 + quad * 8];
#pragma unroll
        for (int mt = 0; mt < 4; ++mt)
#pragma unroll
            for (int nt = 0; nt < 4; ++nt)
                acc[mt][nt] = __builtin_amdgcn_mfma_f32_16x16x32_bf16(
                    af[mt], bfr[nt], acc[mt][nt], 0, 0, 0);
    }

    float rmax[4][4];
#pragma unroll
    for (int mt = 0; mt < 4; ++mt)
#pragma unroll
        for (int reg = 0; reg < 4; ++reg) {
            float m = 0.f;
#pragma unroll
            for (int nt = 0; nt < 4; ++nt)
                m = fmaxf(m, fabsf(acc[mt][nt][reg]));
            rmax[mt][reg] = m;
        }
#pragma unroll
    for (int s = 1; s <= 8; s <<= 1)
#pragma unroll
        for (int mt = 0; mt < 4; ++mt)
#pragma unroll
            for (int reg = 0; reg < 4; ++reg)
                rmax[mt][reg] = fmaxf(rmax[mt][reg], __shfl_xor(rmax[mt][reg], s));
    if (l < 4) {
#pragma unroll
        for (int mt = 0; mt < 4; ++mt)
            red[wc][wr * 64 + mt * 16 + quad * 4 + l] = rmax[mt][l];
    }
    __syncthreads();
    if (tid < 128) {
        float m = fmaxf(fmaxf(red[0][tid], red[1][tid]),
                        fmaxf(red[2][tid], red[3][tid]));
        fin[tid] = m;
        int r = m0 + tid;
        if (r < M) s1[r] = m * (1.f / 127.f);
    }
    __syncthreads();

#pragma unroll
    for (int mt = 0; mt < 4; ++mt)
#pragma unroll
        for (int reg = 0; reg < 4; ++reg) {
            int rl = wr * 64 + mt * 16 + quad * 4 + reg;
            int r = m0 + rl;
            if (r >= M) continue;
            float m = fin[rl];
            float inv = m > 0.f ? 127.f / m : 0.f;
#pragma unroll
            for (int nt = 0; nt < 4; ++nt) {
                int c = wc * 64 + nt * 16 + l;
                Q[(size_t)r * 256 + c] =
                    (unsigned char)((int)rintf(acc[mt][nt][reg] * inv) + 128);
            }
        }
}

// ---------------------------------------------------------------------------
// GEMM2+quant: Q[M,64] biased-u8, s2[M] from A[M,256] bf16 @ Bt[64,256]^T.
// BM=128, BN=64, BK=32; 256 threads = 4 waves 2x2. Pipelined.
__global__ __launch_bounds__(256, 4)
void gemm2_q(const ushort* __restrict__ A, const ushort* __restrict__ Bt,
             unsigned char* __restrict__ Q, float* __restrict__ s2, int M) {
    constexpr int K = 256;
    __shared__ ushort As[128 * 40];
    __shared__ ushort Bs[64 * 40];
    __shared__ float red[2][128];
    __shared__ float fin[128];
    const int tid = threadIdx.x;
    const int wave = tid >> 6, lane = tid & 63;
    const int quad = lane >> 4, l = lane & 15;
    const int wr = wave >> 1, wc = wave & 1;
    const int m0 = blockIdx.x * 128;

    const int crow = tid >> 2;
    const int cpart = (tid & 3) * 8;
    const size_t aoff0 = (size_t)min(m0 + crow, M - 1) * K + cpart;
    const size_t aoff1 = (size_t)min(m0 + crow + 64, M - 1) * K + cpart;
    const size_t boff  = (size_t)crow * K + cpart;

    f32x4 acc[4][2] = {};

    uint4 a0 = *(const uint4*)(A + aoff0);
    uint4 a1 = *(const uint4*)(A + aoff1);
    uint4 b0 = *(const uint4*)(Bt + boff);

    for (int k0 = 0; k0 < K; k0 += 32) {
        __syncthreads();
        *(uint4*)&As[crow * 40 + cpart] = a0;
        *(uint4*)&As[(crow + 64) * 40 + cpart] = a1;
        *(uint4*)&Bs[crow * 40 + cpart] = b0;
        __syncthreads();

        if (k0 + 32 < K) {
            a0 = *(const uint4*)(A + aoff0 + k0 + 32);
            a1 = *(const uint4*)(A + aoff1 + k0 + 32);
            b0 = *(const uint4*)(Bt + boff + k0 + 32);
        }

        bf16x8 af[4], bfr[2];
        const ushort* ab = &As[(wr * 64 + l) * 40 + quad * 8];
#pragma unroll
        for (int mt = 0; mt < 4; ++mt)
            af[mt] = *(const bf16x8*)(ab + mt * 16 * 40);
        const ushort* bb = &Bs[(wc * 32 + l) * 40 + quad * 8];
#pragma unroll
        for (int nt = 0; nt < 2; ++nt)
            bfr[nt] = *(const bf16x8*)(bb + nt * 16 * 40);
#pragma unroll
        for (int mt = 0; mt < 4; ++mt)
#pragma unroll
            for (int nt = 0; nt < 2; ++nt)
                acc[mt][nt] = __builtin_amdgcn_mfma_f32_16x16x32_bf16(
                    af[mt], bfr[nt], acc[mt][nt], 0, 0, 0);
    }

    float rmax[4][4];
#pragma unroll
    for (int mt = 0; mt < 4; ++mt)
#pragma unroll
        for (int reg = 0; reg < 4; ++reg)
            rmax[mt][reg] = fmaxf(fabsf(acc[mt][0][reg]), fabsf(acc[mt][1][reg]));
#pragma unroll
    for (int s = 1; s <= 8; s <<= 1)
#pragma unroll
        for (int mt = 0; mt < 4; ++mt)
#pragma unroll
            for (int reg = 0; reg < 4; ++reg)
                rmax[mt][reg] = fmaxf(rmax[mt][reg], __shfl_xor(rmax[mt][reg], s));
    if (l < 4) {
#pragma unroll
        for (int mt = 0; mt < 4; ++mt)
            red[wc][wr * 64 + mt * 16 + quad * 4 + l] = rmax[mt][l];
    }
    __syncthreads();
    if (tid < 128) {
        float m = fmaxf(red[0][tid], red[1][tid]);
        fin[tid] = m;
        int r = m0 + tid;
        if (r < M) s2[r] = m * (1.f / 127.f);
    }
    __syncthreads();

#pragma unroll
    for (int mt = 0; mt < 4; ++mt)
#pragma unroll
        for (int reg = 0; reg < 4; ++reg) {
            int rl = wr * 64 + mt * 16 + quad * 4 + reg;
            int r = m0 + rl;
            if (r >= M) continue;
            float m = fin[rl];
            float inv = m > 0.f ? 127.f / m : 0.f;
#pragma unroll
            for (int nt = 0; nt < 2; ++nt) {
                int c = wc * 32 + nt * 16 + l;
                Q[(size_t)r * 64 + c] =
                    (unsigned char)((int)rintf(acc[mt][nt][reg] * inv) + 128);
            }
        }
}

// ---------------------------------------------------------------------------
// SpMM layer1: H = relu(A@deq(Q1)+b1). Wave per node. 16B/lane gather:
// lane = {edge slot g=lane>>4, feature block fl=lane&15}; one uint4 gather
// covers 4 edges x 256B rows per instruction. Meta = 4B {w15|col17},
// nontemporal (no L2 pollution); H store nontemporal. Q gathers cached.
__global__ __launch_bounds__(256)
void spmm1_q(const unsigned char* __restrict__ Q, const uint* __restrict__ ewc,
             const int* __restrict__ rp, const float* __restrict__ bias,
             ushort* __restrict__ H, int n) {
    const int wave = threadIdx.x >> 6;
    const int lane = threadIdx.x & 63;
    const int node = blockIdx.x * 4 + wave;
    if (node >= n) return;
    const int e0 = rp[node], e1 = rp[node + 1];
    const int g = lane >> 4;            // edge slot 0..3
    const int fb = (lane & 15) * 16;    // byte offset of 16 features

    float acc[16] = {};
    float sumw = 0.f;
    int e = e0;
    // main: 16 edges per iter, unmasked
    for (; e + 16 <= e1; e += 16) {
#pragma unroll
        for (int u = 0; u < 4; ++u) {
            uint p = __builtin_nontemporal_load(ewc + e + u * 4 + g);
            float w = __uint_as_float(p & 0xFFFE0000u);
            uint4 qv = *(const uint4*)(Q + ((size_t)((p & 0x1FFFFu) << 8)) + fb);
            sumw += w;
            fma4(&acc[0], qv.x, w);
            fma4(&acc[4], qv.y, w);
            fma4(&acc[8], qv.z, w);
            fma4(&acc[12], qv.w, w);
        }
    }
    // tail: 4 edges per iter, masked (ewc padded by 16 entries)
    for (; e < e1; e += 4) {
        int idx = e + g;
        uint p = __builtin_nontemporal_load(ewc + idx);
        bool ok = idx < e1;
        float w = ok ? __uint_as_float(p & 0xFFFE0000u) : 0.f;
        uint off = ok ? ((p & 0x1FFFFu) << 8) : 0u;
        uint4 qv = *(const uint4*)(Q + (size_t)off + fb);
        sumw += w;
        fma4(&acc[0], qv.x, w);
        fma4(&acc[4], qv.y, w);
        fma4(&acc[8], qv.z, w);
        fma4(&acc[12], qv.w, w);
    }

    // reduce edge slots: butterfly across lane groups of 16
#pragma unroll
    for (int s = 16; s <= 32; s <<= 1) {
#pragma unroll
        for (int j = 0; j < 16; ++j)
            acc[j] += __shfl_xor(acc[j], s);
        sumw += __shfl_xor(sumw, s);
    }

    if (g == 0) {
        const int f0 = (lane & 15) * 16;
        float4 b0 = *(const float4*)(bias + f0);
        float4 b1 = *(const float4*)(bias + f0 + 4);
        float4 b2 = *(const float4*)(bias + f0 + 8);
        float4 b3 = *(const float4*)(bias + f0 + 12);
        float bb[16] = {b0.x, b0.y, b0.z, b0.w, b1.x, b1.y, b1.z, b1.w,
                        b2.x, b2.y, b2.z, b2.w, b3.x, b3.y, b3.z, b3.w};
        float fix = -128.f * sumw;
        ushort r[16];
#pragma unroll
        for (int j = 0; j < 16; ++j)
            r[j] = f2b(fmaxf(acc[j] + fix + bb[j], 0.f));
        u32x4 w0, w1;
        w0.x = (uint)r[0] | ((uint)r[1] << 16);
        w0.y = (uint)r[2] | ((uint)r[3] << 16);
        w0.z = (uint)r[4] | ((uint)r[5] << 16);
        w0.w = (uint)r[6] | ((uint)r[7] << 16);
        w1.x = (uint)r[8] | ((uint)r[9] << 16);
        w1.y = (uint)r[10] | ((uint)r[11] << 16);
        w1.z = (uint)r[12] | ((uint)r[13] << 16);
        w1.w = (uint)r[14] | ((uint)r[15] << 16);
        ushort* hp = H + (size_t)node * 256 + f0;
        __builtin_nontemporal_store(w0, (u32x4*)hp);
        __builtin_nontemporal_store(w1, (u32x4*)(hp + 8));
    }
}

// ---------------------------------------------------------------------------
// SpMM layer2: out = A@deq(Q2)+b2. Wave per node. 8B/lane gather: lane =
// {edge slot g=lane>>3, feature block fl=lane&7}; one uint2 gather covers
// 8 edges x 64B rows. NT meta / NT out; butterfly s=8,16,32.
__global__ __launch_bounds__(256)
void spmm2_q(const unsigned char* __restrict__ Q, const uint* __restrict__ ewc,
             const int* __restrict__ rp, const float* __restrict__ bias,
             float* __restrict__ O, int n) {
    const int wave = threadIdx.x >> 6;
    const int lane = threadIdx.x & 63;
    const int node = blockIdx.x * 4 + wave;
    if (node >= n) return;
    const int e0 = rp[node], e1 = rp[node + 1];
    const int g = lane >> 3;           // edge slot 0..7
    const int fb = (lane & 7) * 8;     // byte offset of 8 features

    float acc[8] = {};
    float sumw = 0.f;
    int e = e0;
    // main: 16 edges per iter, unmasked
    for (; e + 16 <= e1; e += 16) {
#pragma unroll
        for (int u = 0; u < 2; ++u) {
            uint p = __builtin_nontemporal_load(ewc + e + u * 8 + g);
            float w = __uint_as_float(p & 0xFFFE0000u);
            uint2 qv = *(const uint2*)(Q + ((size_t)((p & 0x1FFFFu) << 6)) + fb);
            sumw += w;
            fma4(&acc[0], qv.x, w);
            fma4(&acc[4], qv.y, w);
        }
    }
    // tail: 8 edges per iter, masked
    for (; e < e1; e += 8) {
        int idx = e + g;
        uint p = __builtin_nontemporal_load(ewc + idx);
        bool ok = idx < e1;
        float w = ok ? __uint_as_float(p & 0xFFFE0000u) : 0.f;
        uint off = ok ? ((p & 0x1FFFFu) << 6) : 0u;
        uint2 qv = *(const uint2*)(Q + (size_t)off + fb);
        sumw += w;
        fma4(&acc[0], qv.x, w);
        fma4(&acc[4], qv.y, w);
    }

#pragma unroll
    for (int s = 8; s <= 32; s <<= 1) {
#pragma unroll
        for (int j = 0; j < 8; ++j)
            acc[j] += __shfl_xor(acc[j], s);
        sumw += __shfl_xor(sumw, s);
    }

    if (g == 0) {
        const int f0 = (lane & 7) * 8;
        float4 b0 = *(const float4*)(bias + f0);
        float4 b1 = *(const float4*)(bias + f0 + 4);
        float fix = -128.f * sumw;
        f32x4 o0, o1;
        o0.x = acc[0] + fix + b0.x;
        o0.y = acc[1] + fix + b0.y;
        o0.z = acc[2] + fix + b0.z;
        o0.w = acc[3] + fix + b0.w;
        o1.x = acc[4] + fix + b1.x;
        o1.y = acc[5] + fix + b1.y;
        o1.z = acc[6] + fix + b1.z;
        o1.w = acc[7] + fix + b1.w;
        float* op = O + (size_t)node * 64 + f0;
        __builtin_nontemporal_store(o0, (f32x4*)op);
        __builtin_nontemporal_store(o1, (f32x4*)(op + 4));
    }
}

// ---------------------------------------------------------------------------
static inline size_t alignup(size_t x) { return (x + 255) & ~(size_t)255; }

extern "C" void kernel_launch(void* const* d_in, const int* in_sizes, int n_in,
                              void* d_out, int out_size, void* d_ws, size_t ws_size,
                              hipStream_t stream) {
    const float* X  = (const float*)d_in[0];
    const float* ev = (const float*)d_in[1];
    const float* W1 = (const float*)d_in[2];
    const float* b1 = (const float*)d_in[3];
    const float* W2 = (const float*)d_in[4];
    const float* b2 = (const float*)d_in[5];
    const int*  row = (const int*)d_in[6];
    const int*  col = (const int*)d_in[7];
    float* out = (float*)d_out;

    const int n = in_sizes[0] / IN_SIZE;   // 100000
    const int E = in_sizes[1];             // 3200000

    char* p = (char*)d_ws;
    ushort* H    = (ushort*)p; p += alignup((size_t)n * HID * 2);
    unsigned char* Q1 = (unsigned char*)p; p += alignup((size_t)n * HID);
    float*  s1   = (float*)p;  p += alignup((size_t)n * 4);
    unsigned char* Q2 = (unsigned char*)p; p += alignup((size_t)n * OUTF);
    float*  s2   = (float*)p;  p += alignup((size_t)n * 4);
    ushort* W1T  = (ushort*)p; p += alignup((size_t)IN_SIZE * HID * 2);
    ushort* W2T  = (ushort*)p; p += alignup((size_t)HID * OUTF * 2);
    int*    rp   = (int*)p;    p += alignup((size_t)(n + 1) * 4);
    uint*   ewc  = (uint*)p;   p += alignup((size_t)(E + 16) * 4);  // +16 pad for masked tail reads

    const int rpB = (n + 1 + 255) / 256;
    setup_kernel<<<rpB + 256 + 64, 256, 0, stream>>>(row, rp, W1, W1T, W2, W2T,
                                                     n, E, rpB);

    // Q1,s1 = u8rowquant(bf16(X) @ W1)
    gemm1_q<<<(n + 127) / 128, 512, 0, stream>>>(X, W1T, Q1, s1, n);

    // ewc = {w15|col17}, w = vals*s1[col]
    prep_pack<<<(E + 255) / 256, 256, 0, stream>>>(ev, col, s1, ewc, E);

    // H = relu(A @ deq(Q1) + b1)
    spmm1_q<<<(n + 3) / 4, 256, 0, stream>>>(Q1, ewc, rp, b1, H, n);

    // Q2,s2 = u8rowquant(H @ W2)
    gemm2_q<<<(n + 127) / 128, 256, 0, stream>>>(H, W2T, Q2, s2, n);

    // ewc = {w15|col17}, w = vals*s2[col]
    prep_pack<<<(E + 255) / 256, 256, 0, stream>>>(ev, col, s2, ewc, E);

    // out = A @ deq(Q2) + b2
    spmm2_q<<<(n + 3) / 4, 256, 0, stream>>>(Q2, ewc, rp, b2, out, n);
}